// Round 12
// baseline (255.231 us; speedup 1.0000x reference)
//
#include <hip/hip_runtime.h>
#include <cstdint>
#include <cstddef>

#define T_SEQ 2048
#define DMODEL 2048
#define HQ 16
#define HKV 4
#define HD 128

typedef __attribute__((ext_vector_type(4))) float f32x4;
typedef __attribute__((ext_vector_type(8))) short bf16x8;
typedef __attribute__((ext_vector_type(4))) short short4v;
typedef __attribute__((ext_vector_type(2))) short short2v;
typedef __attribute__((ext_vector_type(4))) unsigned uint4v;

#define SBAR() __builtin_amdgcn_s_barrier()
#define SFEN() __builtin_amdgcn_sched_barrier(0)

__device__ __forceinline__ short f2bf(float f) {
  unsigned u = __builtin_bit_cast(unsigned, f);
  u = (u + 0x7FFFu + ((u >> 16) & 1u)) >> 16;
  return (short)u;
}
__device__ __forceinline__ float bf2f(short s) {
  unsigned u = ((unsigned)(unsigned short)s) << 16;
  return __builtin_bit_cast(float, u);
}
__device__ __forceinline__ unsigned pk_hi16(float a, float b) {
  return __builtin_amdgcn_perm(__builtin_bit_cast(unsigned, b),
                               __builtin_bit_cast(unsigned, a), 0x07060302u);
}

__device__ __forceinline__ void g2lds16(const void* g, void* l) {
  __builtin_amdgcn_global_load_lds(
      (const __attribute__((address_space(1))) void*)g,
      (__attribute__((address_space(3))) void*)l, 16, 0, 0);
}

// ---------------- convert f32 -> bf16 ----------------
__global__ void cvt_kernel(const float* __restrict__ src, short* __restrict__ dst, int n) {
  int idx = blockIdx.x * 256 + threadIdx.x;
  int i = idx * 4;
  if (i >= n) return;
  float4 v = *(const float4*)(src + i);
  short4v o;
  o[0] = f2bf(v.x); o[1] = f2bf(v.y); o[2] = f2bf(v.z); o[3] = f2bf(v.w);
  *(short4v*)(dst + i) = o;
}

// ---------------- batched transpose+convert: 4 weights in one launch ----------------
__global__ void transpose_cvt4(const float* __restrict__ s0, const float* __restrict__ s1,
                               const float* __restrict__ s2, const float* __restrict__ s3,
                               short* __restrict__ d0, short* __restrict__ d1,
                               short* __restrict__ d2, short* __restrict__ d3) {
  __shared__ float tile[32][33];
  const int z = blockIdx.z;
  const float* src = (z == 0) ? s0 : (z == 1) ? s1 : (z == 2) ? s2 : s3;
  short* dst = (z == 0) ? d0 : (z == 1) ? d1 : (z == 2) ? d2 : d3;
  const int C = (z == 1 || z == 2) ? 512 : 2048;
  const int R = 2048;
  int c0 = blockIdx.x * 32, r0 = blockIdx.y * 32;
  if (c0 >= C) return;
  int tx = threadIdx.x, ty = threadIdx.y;
  #pragma unroll
  for (int i = 0; i < 32; i += 8)
    tile[ty + i][tx] = src[(size_t)(r0 + ty + i) * C + c0 + tx];
  __syncthreads();
  #pragma unroll
  for (int i = 0; i < 32; i += 8)
    dst[(size_t)(c0 + ty + i) * R + r0 + tx] = f2bf(tile[tx][ty + i]);
}

// ---------------- 4-phase counted-vmcnt GEMM: BM=256, BN=128, BK=64 ----------------
// C[M][N] = A[M][K] * B, BT = B^T [N][K]. 512 thr = 8 waves (4M x 2N), wave out 64x64.
// LDS 96KB: A 2buf x [256][64], B 2buf x [128][64], st_16x32-style swizzle
// (chunk-bit1 ^= row-bit3) applied via pre-swizzled global source + swizzled ds_read.
// Per K-step: 4 quadrant phases; prefetch of K-step t+2 issued into buf[t&1] only
// after the phase-barrier that closes each region's reads; vmcnt(6) once per step.
// MODE 1: f32 C0 (ldc=N). MODE 2: qkv split at 128-col granularity.
template <int MODE>
__global__ __launch_bounds__(512, 1) void gemm256(
    const short* __restrict__ A, const short* __restrict__ BT,
    void* __restrict__ C0, void* __restrict__ C1, void* __restrict__ C2,
    int M, int N, int K)
{
  __shared__ short As[2][256 * 64];   // 64 KB
  __shared__ short Bs[2][128 * 64];   // 32 KB
  const int tid = threadIdx.x;
  const int lane = tid & 63, wid = tid >> 6;
  const int l15 = lane & 15, g = lane >> 4;
  const int wr = wid >> 1, wc = wid & 1;            // 4M x 2N wave grid
  const int bm0 = blockIdx.y * 256, bn0 = blockIdx.x * 128;

  // staging mapping: thread handles chunk qloc of a 32-row span (2 stripes)
  const int qloc = (wid & 3) * 64 + lane;           // 0..255
  const int r_in = ((qloc >> 7) << 4) + ((qloc >> 2) & 15);
  const int c8s  = (((qloc >> 6) & 1) << 2) +
                   ((qloc & 3) ^ ((((qloc >> 2) & 15) >> 3) << 1));
  const int wg   = wid >> 2;                        // span selector within call
  const int ldsl = (wid & 3) * 1024;                // lane-linear dest (bytes), +row0*128

  // swizzled ds_read chunk offset within a (16row x 64col) subtile pair
  const int rdoff = l15 * 4 + (g ^ ((l15 >> 3) << 1));

  auto stageA = [&](int c, int k0, int nb) {
    int row0 = (c < 2) ? ((c * 2 + wg) * 64) : (((c - 2) * 2 + wg) * 64 + 32);
    g2lds16(A + (size_t)(bm0 + row0 + r_in) * K + k0 + c8s * 8,
            (char*)As[nb] + row0 * 128 + ldsl);
  };
  auto stageB = [&](int c, int k0, int nb) {
    int row0 = wg * 64 + c * 32;
    g2lds16(BT + (size_t)(bn0 + row0 + r_in) * K + k0 + c8s * 8,
            (char*)Bs[nb] + row0 * 128 + ldsl);
  };
  auto readA = [&](int mi, int kk, int nb) -> bf16x8 {
    int p = ((wr * 4 + mi) * 2 + kk) * 64 + rdoff;
    return *(const bf16x8*)((const char*)As[nb] + p * 16);
  };
  auto readB = [&](int ni, int kk, int nb) -> bf16x8 {
    int p = ((wc * 4 + ni) * 2 + kk) * 64 + rdoff;
    return *(const bf16x8*)((const char*)Bs[nb] + p * 16);
  };

  f32x4 acc[4][4] = {};
  const int nk = K >> 6;

  // prologue: stage K-step 0 -> buf0, K-step 1 -> buf1
  #pragma unroll
  for (int c = 0; c < 4; c++) stageA(c, 0, 0);
  #pragma unroll
  for (int c = 0; c < 2; c++) stageB(c, 0, 0);
  #pragma unroll
  for (int c = 0; c < 4; c++) stageA(c, 64, 1);
  #pragma unroll
  for (int c = 0; c < 2; c++) stageB(c, 64, 1);
  asm volatile("s_waitcnt vmcnt(6)" ::: "memory");
  SFEN(); SBAR(); SFEN();

  for (int t = 0; t < nk; t++) {
    const int nb = t & 1;
    const int kp = (t + 2) << 6;
    const bool pre = (t + 2) < nk;
    bf16x8 aLO[2][2], aHI[2][2], bLO[2][2], bHI[2][2];

    // ---- P1: read A-lo + B-lo, MFMA (loM x loN) ----
    #pragma unroll
    for (int mi = 0; mi < 2; mi++)
      #pragma unroll
      for (int kk = 0; kk < 2; kk++) aLO[mi][kk] = readA(mi, kk, nb);
    #pragma unroll
    for (int ni = 0; ni < 2; ni++)
      #pragma unroll
      for (int kk = 0; kk < 2; kk++) bLO[ni][kk] = readB(ni, kk, nb);
    __builtin_amdgcn_s_setprio(1);
    #pragma unroll
    for (int kk = 0; kk < 2; kk++)
      #pragma unroll
      for (int mi = 0; mi < 2; mi++)
        #pragma unroll
        for (int ni = 0; ni < 2; ni++)
          acc[mi][ni] = __builtin_amdgcn_mfma_f32_16x16x32_bf16(aLO[mi][kk], bLO[ni][kk], acc[mi][ni], 0, 0, 0);
    __builtin_amdgcn_s_setprio(0);
    SFEN(); SBAR(); SFEN();

    // ---- P2: read B-hi; prefetch A-even + B-even of t+2; MFMA (loM x hiN) ----
    #pragma unroll
    for (int ni = 0; ni < 2; ni++)
      #pragma unroll
      for (int kk = 0; kk < 2; kk++) bHI[ni][kk] = readB(ni + 2, kk, nb);
    if (pre) { stageA(0, kp, nb); stageA(1, kp, nb); stageB(0, kp, nb); }
    __builtin_amdgcn_s_setprio(1);
    #pragma unroll
    for (int kk = 0; kk < 2; kk++)
      #pragma unroll
      for (int mi = 0; mi < 2; mi++)
        #pragma unroll
        for (int ni = 0; ni < 2; ni++)
          acc[mi][ni + 2] = __builtin_amdgcn_mfma_f32_16x16x32_bf16(aLO[mi][kk], bHI[ni][kk], acc[mi][ni + 2], 0, 0, 0);
    __builtin_amdgcn_s_setprio(0);
    SFEN(); SBAR(); SFEN();

    // ---- P3: read A-hi; prefetch B-odd; MFMA (hiM x loN) ----
    #pragma unroll
    for (int mi = 0; mi < 2; mi++)
      #pragma unroll
      for (int kk = 0; kk < 2; kk++) aHI[mi][kk] = readA(mi + 2, kk, nb);
    if (pre) stageB(1, kp, nb);
    __builtin_amdgcn_s_setprio(1);
    #pragma unroll
    for (int kk = 0; kk < 2; kk++)
      #pragma unroll
      for (int mi = 0; mi < 2; mi++)
        #pragma unroll
        for (int ni = 0; ni < 2; ni++)
          acc[mi + 2][ni] = __builtin_amdgcn_mfma_f32_16x16x32_bf16(aHI[mi][kk], bLO[ni][kk], acc[mi + 2][ni], 0, 0, 0);
    __builtin_amdgcn_s_setprio(0);
    SFEN(); SBAR(); SFEN();

    // ---- P4: prefetch A-odd; MFMA (hiM x hiN); counted drain ----
    if (pre) { stageA(2, kp, nb); stageA(3, kp, nb); }
    __builtin_amdgcn_s_setprio(1);
    #pragma unroll
    for (int kk = 0; kk < 2; kk++)
      #pragma unroll
      for (int mi = 0; mi < 2; mi++)
        #pragma unroll
        for (int ni = 0; ni < 2; ni++)
          acc[mi + 2][ni + 2] = __builtin_amdgcn_mfma_f32_16x16x32_bf16(aHI[mi][kk], bHI[ni][kk], acc[mi + 2][ni + 2], 0, 0, 0);
    __builtin_amdgcn_s_setprio(0);
    if (pre) { asm volatile("s_waitcnt vmcnt(6)" ::: "memory"); }
    else     { asm volatile("s_waitcnt vmcnt(0)" ::: "memory"); }
    SFEN(); SBAR(); SFEN();
  }

  // epilogue
  if (MODE == 1) {
    float* C = (float*)C0;
    #pragma unroll
    for (int mi = 0; mi < 4; mi++)
      #pragma unroll
      for (int r = 0; r < 4; r++) {
        int m = bm0 + wr * 64 + mi * 16 + g * 4 + r;
        #pragma unroll
        for (int ni = 0; ni < 4; ni++)
          C[(size_t)m * N + bn0 + wc * 64 + ni * 16 + l15] = acc[mi][ni][r];
      }
  } else {
    short* Cb; int ldc, nc;
    if (bn0 < 2048)      { Cb = (short*)C0; ldc = 2048; nc = bn0; }
    else if (bn0 < 2560) { Cb = (short*)C1; ldc = 512;  nc = bn0 - 2048; }
    else                 { Cb = (short*)C2; ldc = 512;  nc = bn0 - 2560; }
    #pragma unroll
    for (int mi = 0; mi < 4; mi++)
      #pragma unroll
      for (int r = 0; r < 4; r++) {
        int m = bm0 + wr * 64 + mi * 16 + g * 4 + r;
        #pragma unroll
        for (int ni = 0; ni < 4; ni++)
          Cb[(size_t)m * ldc + nc + wc * 64 + ni * 16 + l15] = f2bf(acc[mi][ni][r]);
      }
  }
}

// ---------------- RoPE, q and k in ONE launch (block-aligned split) ----------------
__global__ void rope_all(short* __restrict__ qbuf, short* __restrict__ kbuf, float qscale) {
  int idx = blockIdx.x * 256 + threadIdx.x;
  short* buf; int NH; float scale;
  if (idx < 4194304) { buf = qbuf; NH = HQ; scale = qscale; }
  else               { buf = kbuf; NH = HKV; scale = 1.0f; idx -= 4194304; }
  int i = idx & 63;
  int th = idx >> 6;
  int t = (th / NH) % T_SEQ;
  size_t base = (size_t)th * 128;
  float invf = exp2f(-(float)i * 0.20762050593046014f);
  float theta = (float)t * invf;
  float sn, cs;
  sincosf(theta, &sn, &cs);
  float a = bf2f(buf[base + i]);
  float b = bf2f(buf[base + 64 + i]);
  buf[base + i]      = f2bf((a * cs - b * sn) * scale);
  buf[base + 64 + i] = f2bf((b * cs + a * sn) * scale);
}

// ---------------- Flash attention (causal, GQA) — round-5 proven config ----------------
__global__ __launch_bounds__(512, 4) void attn_kernel(
    const short* __restrict__ qg, const short* __restrict__ kg,
    const short* __restrict__ vg, short* __restrict__ og)
{
  __shared__ short Ks[2][64 * 128];  // 32 KB
  __shared__ short Vt[128 * 64];     // 16 KB
  const int tid = threadIdx.x;
  const int lane = tid & 63, w = tid >> 6;          // 8 waves
  const int l15 = lane & 15, g = lane >> 4;
  const int b = blockIdx.z;
  const int qti = b ? (15 - (int)blockIdx.x) : (int)blockIdx.x;
  const int qt0 = qti * 128;
  const int h = blockIdx.y, hk = h >> 2;
  const int qw0 = qt0 + w * 16;

  bf16x8 qf[4];
  {
    size_t t = (size_t)b * T_SEQ + qw0 + l15;
    const short* qp = qg + (t * HQ + h) * HD;
    #pragma unroll
    for (int ks = 0; ks < 4; ks++)
      qf[ks] = *(const bf16x8*)(qp + ks * 32 + g * 8);
  }

  f32x4 of[8] = {};
  float m2 = -INFINITY;
  float ls = 0.f;

  const short* kbase = kg + ((size_t)b * T_SEQ * HKV + hk) * HD;
  const short* vbase = vg + ((size_t)b * T_SEQ * HKV + hk) * HD;

  const int kv2 = (tid & 31) * 2;
  const int d8s = (tid >> 5) * 8;
  const int p0 = (kv2 >> 5) * 32 + ((kv2 & 15) >> 2) * 8 + ((kv2 >> 4) & 1) * 4 + (kv2 & 3);
  const int nt = (qt0 + 128) >> 6;

  bf16x8 vr[2];

  auto stageK = [&](int t, int nb) {
    #pragma unroll
    for (int call = 0; call < 2; call++) {
      int tau = call * 512 + tid;
      int kv = tau >> 4, c = tau & 15;
      g2lds16(kbase + (size_t)(t * 64 + kv) * (HKV * HD) + ((c ^ (kv & 7)) << 3),
              (char*)Ks[nb] + call * 8192 + w * 1024);
    }
  };
  auto loadV = [&](int t) {
    const short* vp = vbase + (size_t)(t * 64 + kv2) * (HKV * HD) + d8s;
    vr[0] = *(const bf16x8*)(vp);
    vr[1] = *(const bf16x8*)(vp + HKV * HD);
  };
  auto writeV = [&]() {
    #pragma unroll
    for (int e = 0; e < 8; e++) {
      int row = d8s + e;
      int addr = row * 64 + (((p0 >> 3) ^ e) << 3) + (p0 & 7);
      short2v t2; t2[0] = vr[0][e]; t2[1] = vr[1][e];
      *(short2v*)(&Vt[addr]) = t2;
    }
  };

  stageK(0, 0);
  loadV(0);
  __syncthreads();
  writeV();
  __syncthreads();

  int cur = 0;
  for (int t = 0; t < nt; t++) {
    const int kv0 = t * 64;
    const bool haveNext = (t + 1 < nt);
    if (haveNext) { loadV(t + 1); stageK(t + 1, cur ^ 1); }

    if (kv0 <= qw0 + 15) {
      const short* Kc = Ks[cur];
      f32x4 sacc[4] = {};
      __builtin_amdgcn_s_setprio(1);
      #pragma unroll
      for (int ks = 0; ks < 4; ks++) {
        bf16x8 kf[4];
        #pragma unroll
        for (int kt = 0; kt < 4; kt++) {
          int row = kt * 16 + l15;
          int ch = (ks * 4 + g) ^ (row & 7);
          kf[kt] = *(const bf16x8*)(Kc + row * 128 + ch * 8);
        }
        #pragma unroll
        for (int kt = 0; kt < 4; kt++)
          sacc[kt] = __builtin_amdgcn_mfma_f32_16x16x32_bf16(kf[kt], qf[ks], sacc[kt], 0, 0, 0);
      }
      __builtin_amdgcn_s_setprio(0);
      const bool needmask = (kv0 + 63) > qw0;
      const int qpos = qw0 + l15;
      float vmax = -INFINITY;
      #pragma unroll
      for (int kt = 0; kt < 4; kt++)
        #pragma unroll
        for (int r = 0; r < 4; r++) {
          int kvpos = kv0 + kt * 16 + g * 4 + r;
          float sv = sacc[kt][r];
          if (needmask && kvpos > qpos) sv = -INFINITY;
          sacc[kt][r] = sv;
          vmax = fmaxf(vmax, sv);
        }
      vmax = fmaxf(vmax, __shfl_xor(vmax, 16));
      vmax = fmaxf(vmax, __shfl_xor(vmax, 32));
      if (!__all(vmax <= m2 + 8.0f)) {
        float mnew = fmaxf(m2, vmax);
        float resc = exp2f(m2 - mnew);
        m2 = mnew;
        ls *= resc;
        #pragma unroll
        for (int dc = 0; dc < 8; dc++) of[dc] *= resc;
      }
      float lsum = 0.f;
      #pragma unroll
      for (int kt = 0; kt < 4; kt++)
        #pragma unroll
        for (int r = 0; r < 4; r++) {
          float p = exp2f(sacc[kt][r] - m2);
          sacc[kt][r] = p;
          lsum += p;
        }
      lsum += __shfl_xor(lsum, 16);
      lsum += __shfl_xor(lsum, 32);
      ls += lsum;
      bf16x8 pb[2];
      #pragma unroll
      for (int ktw = 0; ktw < 2; ktw++) {
        uint4v pw;
        pw[0] = pk_hi16(sacc[2 * ktw][0], sacc[2 * ktw][1]);
        pw[1] = pk_hi16(sacc[2 * ktw][2], sacc[2 * ktw][3]);
        pw[2] = pk_hi16(sacc[2 * ktw + 1][0], sacc[2 * ktw + 1][1]);
        pw[3] = pk_hi16(sacc[2 * ktw + 1][2], sacc[2 * ktw + 1][3]);
        pb[ktw] = __builtin_bit_cast(bf16x8, pw);
      }
      __builtin_amdgcn_s_setprio(1);
      #pragma unroll
      for (int ktw = 0; ktw < 2; ktw++)
        #pragma unroll
        for (int dc = 0; dc < 8; dc++) {
          int row = dc * 16 + l15;
          bf16x8 vf = *(const bf16x8*)(&Vt[row * 64 + ((ktw * 32 + g * 8) ^ ((l15 & 7) << 3))]);
          of[dc] = __builtin_amdgcn_mfma_f32_16x16x32_bf16(vf, pb[ktw], of[dc], 0, 0, 0);
        }
      __builtin_amdgcn_s_setprio(0);
    }

    __syncthreads();
    if (haveNext) writeV();
    __syncthreads();
    cur ^= 1;
  }

  {
    float inv = 1.0f / ls;
    size_t t = (size_t)b * T_SEQ + qw0 + l15;
    short* op = og + (t * HQ + h) * HD;
    #pragma unroll
    for (int dc = 0; dc < 8; dc++) {
      short4v o;
      #pragma unroll
      for (int r = 0; r < 4; r++) o[r] = f2bf(of[dc][r] * inv);
      *(short4v*)(op + dc * 16 + g * 4) = o;
    }
  }
}

extern "C" void kernel_launch(void* const* d_in, const int* in_sizes, int n_in,
                              void* d_out, int out_size, void* d_ws, size_t ws_size,
                              hipStream_t stream) {
  (void)in_sizes; (void)n_in; (void)out_size; (void)ws_size;
  const float* x  = (const float*)d_in[0];
  const float* Wq = (const float*)d_in[2];
  const float* Wk = (const float*)d_in[3];
  const float* Wv = (const float*)d_in[4];
  const float* Wo = (const float*)d_in[5];

  char* ws = (char*)d_ws;
  short* xb   = (short*)(ws);                    // 16 MB   [4096][2048]
  short* wall = (short*)(ws + 16777216);         // 12.6 MB [3072][2048] = WqT|WkT|WvT
  short* wkT  = wall + (size_t)2048 * 2048;
  short* wvT  = wall + (size_t)2560 * 2048;
  short* woT  = (short*)(ws + 29360128);         // 8 MB    [2048][2048]
  short* qb   = (short*)(ws + 37748736);         // 16 MB   [B,T,HQ,128]
  short* kb   = (short*)(ws + 54525952);         // 4 MB    [B,T,HKV,128]
  short* vb   = (short*)(ws + 58720256);         // 4 MB    [B,T,HKV,128]
  short* ab   = (short*)(ws + 62914560);         // 16 MB   [4096][2048]

  const float MULT = 0.08838834764831845f;
  const float LOG2E = 1.4426950408889634f;
  const float QSCALE = MULT * LOG2E;

  dim3 tb(32, 8);
  cvt_kernel<<<8192, 256, 0, stream>>>(x, xb, 8388608);
  transpose_cvt4<<<dim3(64, 64, 4), tb, 0, stream>>>(Wq, Wk, Wv, Wo, wall, wkT, wvT, woT);

  // fused QKV projection: [4096][2048] x [2048][3072] -> qb|kb|vb
  gemm256<2><<<dim3(24, 16), 512, 0, stream>>>(xb, wall, qb, kb, vb, 4096, 3072, 2048);

  rope_all<<<20480, 256, 0, stream>>>(qb, kb, QSCALE);

  attn_kernel<<<dim3(16, 16, 2), 512, 0, stream>>>(qb, kb, vb, ab);

  gemm256<1><<<dim3(16, 16), 512, 0, stream>>>(ab, woT, d_out, nullptr, nullptr, 4096, 2048, 2048);
}

// Round 13
// 206.430 us; speedup vs baseline: 1.2364x; 1.2364x over previous
//
#include <hip/hip_runtime.h>
#include <cstdint>
#include <cstddef>

#define T_SEQ 2048
#define DMODEL 2048
#define HQ 16
#define HKV 4
#define HD 128

typedef __attribute__((ext_vector_type(4))) float f32x4;
typedef __attribute__((ext_vector_type(8))) short bf16x8;
typedef __attribute__((ext_vector_type(4))) short short4v;
typedef __attribute__((ext_vector_type(2))) short short2v;
typedef __attribute__((ext_vector_type(4))) unsigned uint4v;

__device__ __forceinline__ short f2bf(float f) {
  unsigned u = __builtin_bit_cast(unsigned, f);
  u = (u + 0x7FFFu + ((u >> 16) & 1u)) >> 16;
  return (short)u;
}
__device__ __forceinline__ float bf2f(short s) {
  unsigned u = ((unsigned)(unsigned short)s) << 16;
  return __builtin_bit_cast(float, u);
}
// pack hi16(a) | hi16(b)<<16 (bf16 truncation) in ONE v_perm_b32
__device__ __forceinline__ unsigned pk_hi16(float a, float b) {
  return __builtin_amdgcn_perm(__builtin_bit_cast(unsigned, b),
                               __builtin_bit_cast(unsigned, a), 0x07060302u);
}

__device__ __forceinline__ void g2lds16(const void* g, void* l) {
  __builtin_amdgcn_global_load_lds(
      (const __attribute__((address_space(1))) void*)g,
      (__attribute__((address_space(3))) void*)l, 16, 0, 0);
}

// ---------------- convert f32 -> bf16 ----------------
__global__ void cvt_kernel(const float* __restrict__ src, short* __restrict__ dst, int n) {
  int idx = blockIdx.x * 256 + threadIdx.x;
  int i = idx * 4;
  if (i >= n) return;
  float4 v = *(const float4*)(src + i);
  short4v o;
  o[0] = f2bf(v.x); o[1] = f2bf(v.y); o[2] = f2bf(v.z); o[3] = f2bf(v.w);
  *(short4v*)(dst + i) = o;
}

// ---------------- batched transpose+convert: 4 weights in one launch ----------------
__global__ void transpose_cvt4(const float* __restrict__ s0, const float* __restrict__ s1,
                               const float* __restrict__ s2, const float* __restrict__ s3,
                               short* __restrict__ d0, short* __restrict__ d1,
                               short* __restrict__ d2, short* __restrict__ d3) {
  __shared__ float tile[32][33];
  const int z = blockIdx.z;
  const float* src = (z == 0) ? s0 : (z == 1) ? s1 : (z == 2) ? s2 : s3;
  short* dst = (z == 0) ? d0 : (z == 1) ? d1 : (z == 2) ? d2 : d3;
  const int C = (z == 1 || z == 2) ? 512 : 2048;
  const int R = 2048;
  int c0 = blockIdx.x * 32, r0 = blockIdx.y * 32;
  if (c0 >= C) return;
  int tx = threadIdx.x, ty = threadIdx.y;
  #pragma unroll
  for (int i = 0; i < 32; i += 8)
    tile[ty + i][tx] = src[(size_t)(r0 + ty + i) * C + c0 + tx];
  __syncthreads();
  #pragma unroll
  for (int i = 0; i < 32; i += 8)
    dst[(size_t)(c0 + ty + i) * R + r0 + tx] = f2bf(tile[tx][ty + i]);
}

// ---------------- GEMM: m97 2-barrier skeleton, BK=64 ----------------
// C = A[M][K] * B, BT = B^T [N][K]. 256 thr = 4 waves (2x2), 128x128 tile.
// LDS 32 KB (A,B each 128x64), 2 blocks/CU. Per K-step: 1 barrier pair,
// 8 global_load_lds, 16 ds_read_b128, 32 MFMA. Chunk swizzle: c ^= row&7
// (pre-swizzled global source, linear LDS dest, swizzled ds_read — 8-sweep floor).
// MODE 1: f32 C0 (ldc=N). MODE 2: qkv split (n0<2048 -> C0, <2560 -> C1, else C2).
template <int MODE>
__global__ __launch_bounds__(256, 2) void gemm_kernel(
    const short* __restrict__ A, const short* __restrict__ BT,
    void* __restrict__ C0, void* __restrict__ C1, void* __restrict__ C2,
    int M, int N, int K)
{
  __shared__ short As[128 * 64];   // 16 KB
  __shared__ short Bs[128 * 64];   // 16 KB
  const int tid = threadIdx.x;
  const int lane = tid & 63, w = tid >> 6;
  const int l15 = lane & 15, g = lane >> 4;
  const int m0 = blockIdx.y * 128, n0 = blockIdx.x * 128;
  const int wm = (w >> 1) * 64, wn = (w & 1) * 64;

  const int srow = tid >> 3;       // 0..31 within a call
  const int sc   = tid & 7;        // chunk 0..7

  f32x4 acc[4][4] = {};

  for (int k0 = 0; k0 < K; k0 += 64) {
    __syncthreads();
    #pragma unroll
    for (int call = 0; call < 4; call++) {
      int row = call * 32 + srow;
      int csw = sc ^ (row & 7);
      g2lds16(A + (size_t)(m0 + row) * K + k0 + csw * 8,
              (char*)As + call * 4096 + w * 1024);
      g2lds16(BT + (size_t)(n0 + row) * K + k0 + csw * 8,
              (char*)Bs + call * 4096 + w * 1024);
    }
    __syncthreads();
    #pragma unroll
    for (int kk = 0; kk < 2; kk++) {
      bf16x8 af[4], bfr[4];
      #pragma unroll
      for (int mi = 0; mi < 4; mi++) {
        int row = wm + mi * 16 + l15;
        int ch = (kk * 4 + g) ^ (row & 7);
        af[mi] = *(const bf16x8*)(As + row * 64 + ch * 8);
      }
      #pragma unroll
      for (int ni = 0; ni < 4; ni++) {
        int row = wn + ni * 16 + l15;
        int ch = (kk * 4 + g) ^ (row & 7);
        bfr[ni] = *(const bf16x8*)(Bs + row * 64 + ch * 8);
      }
      #pragma unroll
      for (int mi = 0; mi < 4; mi++)
        #pragma unroll
        for (int ni = 0; ni < 4; ni++)
          acc[mi][ni] = __builtin_amdgcn_mfma_f32_16x16x32_bf16(af[mi], bfr[ni], acc[mi][ni], 0, 0, 0);
    }
  }

  if (MODE == 1) {
    float* C = (float*)C0;
    #pragma unroll
    for (int mi = 0; mi < 4; mi++)
      #pragma unroll
      for (int r = 0; r < 4; r++) {
        int m = m0 + wm + mi * 16 + g * 4 + r;
        #pragma unroll
        for (int ni = 0; ni < 4; ni++)
          C[(size_t)m * N + n0 + wn + ni * 16 + l15] = acc[mi][ni][r];
      }
  } else {
    short* Cb; int ldc, nc;
    if (n0 < 2048)      { Cb = (short*)C0; ldc = 2048; nc = n0; }
    else if (n0 < 2560) { Cb = (short*)C1; ldc = 512;  nc = n0 - 2048; }
    else                { Cb = (short*)C2; ldc = 512;  nc = n0 - 2560; }
    #pragma unroll
    for (int mi = 0; mi < 4; mi++)
      #pragma unroll
      for (int r = 0; r < 4; r++) {
        int m = m0 + wm + mi * 16 + g * 4 + r;
        #pragma unroll
        for (int ni = 0; ni < 4; ni++)
          Cb[(size_t)m * ldc + nc + wn + ni * 16 + l15] = f2bf(acc[mi][ni][r]);
      }
  }
}

// ---------------- RoPE, q and k in ONE launch (block-aligned split) ----------------
__global__ void rope_all(short* __restrict__ qbuf, short* __restrict__ kbuf, float qscale) {
  int idx = blockIdx.x * 256 + threadIdx.x;
  short* buf; int NH; float scale;
  if (idx < 4194304) { buf = qbuf; NH = HQ; scale = qscale; }
  else               { buf = kbuf; NH = HKV; scale = 1.0f; idx -= 4194304; }
  int i = idx & 63;
  int th = idx >> 6;
  int t = (th / NH) % T_SEQ;
  size_t base = (size_t)th * 128;
  float invf = exp2f(-(float)i * 0.20762050593046014f);
  float theta = (float)t * invf;
  float sn, cs;
  sincosf(theta, &sn, &cs);
  float a = bf2f(buf[base + i]);
  float b = bf2f(buf[base + 64 + i]);
  buf[base + i]      = f2bf((a * cs - b * sn) * scale);
  buf[base + 64 + i] = f2bf((b * cs + a * sn) * scale);
}

// ---------------- Flash attention (causal, GQA) — round-5 proven config (91 us) ----------------
__global__ __launch_bounds__(512, 4) void attn_kernel(
    const short* __restrict__ qg, const short* __restrict__ kg,
    const short* __restrict__ vg, short* __restrict__ og)
{
  __shared__ short Ks[2][64 * 128];  // 32 KB
  __shared__ short Vt[128 * 64];     // 16 KB
  const int tid = threadIdx.x;
  const int lane = tid & 63, w = tid >> 6;          // 8 waves
  const int l15 = lane & 15, g = lane >> 4;
  const int b = blockIdx.z;
  const int qti = b ? (15 - (int)blockIdx.x) : (int)blockIdx.x;
  const int qt0 = qti * 128;
  const int h = blockIdx.y, hk = h >> 2;
  const int qw0 = qt0 + w * 16;

  bf16x8 qf[4];
  {
    size_t t = (size_t)b * T_SEQ + qw0 + l15;
    const short* qp = qg + (t * HQ + h) * HD;
    #pragma unroll
    for (int ks = 0; ks < 4; ks++)
      qf[ks] = *(const bf16x8*)(qp + ks * 32 + g * 8);
  }

  f32x4 of[8] = {};
  float m2 = -INFINITY;
  float ls = 0.f;

  const short* kbase = kg + ((size_t)b * T_SEQ * HKV + hk) * HD;
  const short* vbase = vg + ((size_t)b * T_SEQ * HKV + hk) * HD;

  const int kv2 = (tid & 31) * 2;
  const int d8s = (tid >> 5) * 8;
  const int p0 = (kv2 >> 5) * 32 + ((kv2 & 15) >> 2) * 8 + ((kv2 >> 4) & 1) * 4 + (kv2 & 3);
  const int nt = (qt0 + 128) >> 6;

  bf16x8 vr[2];

  auto stageK = [&](int t, int nb) {
    #pragma unroll
    for (int call = 0; call < 2; call++) {
      int tau = call * 512 + tid;
      int kv = tau >> 4, c = tau & 15;
      g2lds16(kbase + (size_t)(t * 64 + kv) * (HKV * HD) + ((c ^ (kv & 7)) << 3),
              (char*)Ks[nb] + call * 8192 + w * 1024);
    }
  };
  auto loadV = [&](int t) {
    const short* vp = vbase + (size_t)(t * 64 + kv2) * (HKV * HD) + d8s;
    vr[0] = *(const bf16x8*)(vp);
    vr[1] = *(const bf16x8*)(vp + HKV * HD);
  };
  auto writeV = [&]() {
    #pragma unroll
    for (int e = 0; e < 8; e++) {
      int row = d8s + e;
      int addr = row * 64 + (((p0 >> 3) ^ e) << 3) + (p0 & 7);
      short2v t2; t2[0] = vr[0][e]; t2[1] = vr[1][e];
      *(short2v*)(&Vt[addr]) = t2;
    }
  };

  stageK(0, 0);
  loadV(0);
  __syncthreads();
  writeV();
  __syncthreads();

  int cur = 0;
  for (int t = 0; t < nt; t++) {
    const int kv0 = t * 64;
    const bool haveNext = (t + 1 < nt);
    if (haveNext) { loadV(t + 1); stageK(t + 1, cur ^ 1); }

    if (kv0 <= qw0 + 15) {
      const short* Kc = Ks[cur];
      f32x4 sacc[4] = {};
      __builtin_amdgcn_s_setprio(1);
      #pragma unroll
      for (int ks = 0; ks < 4; ks++) {
        bf16x8 kf[4];
        #pragma unroll
        for (int kt = 0; kt < 4; kt++) {
          int row = kt * 16 + l15;
          int ch = (ks * 4 + g) ^ (row & 7);
          kf[kt] = *(const bf16x8*)(Kc + row * 128 + ch * 8);
        }
        #pragma unroll
        for (int kt = 0; kt < 4; kt++)
          sacc[kt] = __builtin_amdgcn_mfma_f32_16x16x32_bf16(kf[kt], qf[ks], sacc[kt], 0, 0, 0);
      }
      __builtin_amdgcn_s_setprio(0);
      const bool needmask = (kv0 + 63) > qw0;
      const int qpos = qw0 + l15;
      float vmax = -INFINITY;
      #pragma unroll
      for (int kt = 0; kt < 4; kt++)
        #pragma unroll
        for (int r = 0; r < 4; r++) {
          int kvpos = kv0 + kt * 16 + g * 4 + r;
          float sv = sacc[kt][r];
          if (needmask && kvpos > qpos) sv = -INFINITY;
          sacc[kt][r] = sv;
          vmax = fmaxf(vmax, sv);
        }
      vmax = fmaxf(vmax, __shfl_xor(vmax, 16));
      vmax = fmaxf(vmax, __shfl_xor(vmax, 32));
      if (!__all(vmax <= m2 + 8.0f)) {
        float mnew = fmaxf(m2, vmax);
        float resc = exp2f(m2 - mnew);
        m2 = mnew;
        ls *= resc;
        #pragma unroll
        for (int dc = 0; dc < 8; dc++) of[dc] *= resc;
      }
      float lsum = 0.f;
      #pragma unroll
      for (int kt = 0; kt < 4; kt++)
        #pragma unroll
        for (int r = 0; r < 4; r++) {
          float p = exp2f(sacc[kt][r] - m2);
          sacc[kt][r] = p;
          lsum += p;
        }
      lsum += __shfl_xor(lsum, 16);
      lsum += __shfl_xor(lsum, 32);
      ls += lsum;
      bf16x8 pb[2];
      #pragma unroll
      for (int ktw = 0; ktw < 2; ktw++) {
        uint4v pw;
        pw[0] = pk_hi16(sacc[2 * ktw][0], sacc[2 * ktw][1]);
        pw[1] = pk_hi16(sacc[2 * ktw][2], sacc[2 * ktw][3]);
        pw[2] = pk_hi16(sacc[2 * ktw + 1][0], sacc[2 * ktw + 1][1]);
        pw[3] = pk_hi16(sacc[2 * ktw + 1][2], sacc[2 * ktw + 1][3]);
        pb[ktw] = __builtin_bit_cast(bf16x8, pw);
      }
      __builtin_amdgcn_s_setprio(1);
      #pragma unroll
      for (int ktw = 0; ktw < 2; ktw++)
        #pragma unroll
        for (int dc = 0; dc < 8; dc++) {
          int row = dc * 16 + l15;
          bf16x8 vf = *(const bf16x8*)(&Vt[row * 64 + ((ktw * 32 + g * 8) ^ ((l15 & 7) << 3))]);
          of[dc] = __builtin_amdgcn_mfma_f32_16x16x32_bf16(vf, pb[ktw], of[dc], 0, 0, 0);
        }
      __builtin_amdgcn_s_setprio(0);
    }

    __syncthreads();
    if (haveNext) writeV();
    __syncthreads();
    cur ^= 1;
  }

  {
    float inv = 1.0f / ls;
    size_t t = (size_t)b * T_SEQ + qw0 + l15;
    short* op = og + (t * HQ + h) * HD;
    #pragma unroll
    for (int dc = 0; dc < 8; dc++) {
      short4v o;
      #pragma unroll
      for (int r = 0; r < 4; r++) o[r] = f2bf(of[dc][r] * inv);
      *(short4v*)(op + dc * 16 + g * 4) = o;
    }
  }
}

extern "C" void kernel_launch(void* const* d_in, const int* in_sizes, int n_in,
                              void* d_out, int out_size, void* d_ws, size_t ws_size,
                              hipStream_t stream) {
  (void)in_sizes; (void)n_in; (void)out_size; (void)ws_size;
  const float* x  = (const float*)d_in[0];
  const float* Wq = (const float*)d_in[2];
  const float* Wk = (const float*)d_in[3];
  const float* Wv = (const float*)d_in[4];
  const float* Wo = (const float*)d_in[5];

  char* ws = (char*)d_ws;
  short* xb   = (short*)(ws);                    // 16 MB   [4096][2048]
  short* wall = (short*)(ws + 16777216);         // 12.6 MB [3072][2048] = WqT|WkT|WvT
  short* wkT  = wall + (size_t)2048 * 2048;
  short* wvT  = wall + (size_t)2560 * 2048;
  short* woT  = (short*)(ws + 29360128);         // 8 MB    [2048][2048]
  short* qb   = (short*)(ws + 37748736);         // 16 MB   [B,T,HQ,128]
  short* kb   = (short*)(ws + 54525952);         // 4 MB    [B,T,HKV,128]
  short* vb   = (short*)(ws + 58720256);         // 4 MB    [B,T,HKV,128]
  short* ab   = (short*)(ws + 62914560);         // 16 MB   [4096][2048]

  const float MULT = 0.08838834764831845f;
  const float LOG2E = 1.4426950408889634f;
  const float QSCALE = MULT * LOG2E;

  dim3 tb(32, 8);
  cvt_kernel<<<8192, 256, 0, stream>>>(x, xb, 8388608);
  transpose_cvt4<<<dim3(64, 64, 4), tb, 0, stream>>>(Wq, Wk, Wv, Wo, wall, wkT, wvT, woT);

  // fused QKV projection: [4096][2048] x [2048][3072] -> qb|kb|vb
  gemm_kernel<2><<<dim3(24, 32), 256, 0, stream>>>(xb, wall, qb, kb, vb, 4096, 3072, 2048);

  rope_all<<<20480, 256, 0, stream>>>(qb, kb, QSCALE);

  attn_kernel<<<dim3(16, 16, 2), 512, 0, stream>>>(qb, kb, vb, ab);

  gemm_kernel<1><<<dim3(16, 32), 256, 0, stream>>>(ab, woT, d_out, nullptr, nullptr, 4096, 2048, 2048);
}